// Round 12
// baseline (203.727 us; speedup 1.0000x reference)
//
#include <hip/hip_runtime.h>
#include <hip/hip_cooperative_groups.h>
#include <math.h>

#define NNV 4096   // N
#define KKV 64     // K
#define BBV 256    // B
#define CHN 256    // n-chunk staged in LDS
#define NCH (NNV / CHN)
#define NPW 10     // stored powers X^1..X^10 -> series terms to p=20

#define OFF_DSROW 98304          // gbuf: [0, 98304)
#define OFF_M2    104448         // dsrow: [98304, 104448)
#define OFF_SRED  120832         // m2: [104448, 120832); sred: [120832, 120992)
#define SMEM_SZ   120992

typedef unsigned short u16;
typedef unsigned int u32;
typedef u32  u32x4  __attribute__((ext_vector_type(4)));
typedef short bf16x8 __attribute__((ext_vector_type(8)));
typedef float f32x4  __attribute__((ext_vector_type(4)));
typedef float f32x16 __attribute__((ext_vector_type(16)));

__device__ inline u16 f2bf(float x) {           // RNE f32 -> bf16
    u32 u = __float_as_uint(x);
    u = u + 0x7FFFu + ((u >> 16) & 1u);
    return (u16)(u >> 16);
}
__device__ inline float bf2f(u16 v) { return __uint_as_float(((u32)v) << 16); }

// ================= fused: prep -> grid.sync -> gram -> grid.sync -> tail =============
__global__ __launch_bounds__(512) void fused(
    const float* __restrict__ targets, const float* __restrict__ rho,
    const float* __restrict__ qs, const float* __restrict__ means,
    const float* __restrict__ C, const float* __restrict__ psi,
    u16* __restrict__ Csbf, u16* __restrict__ dsbf,
    u32* __restrict__ mask2, float* __restrict__ scal,
    float* __restrict__ Apart, float* __restrict__ Upart,
    float* __restrict__ out) {
    __shared__ __align__(16) char smem[SMEM_SZ];
    cooperative_groups::grid_group grid = cooperative_groups::this_grid();

    const int t = threadIdx.x;
    const int lane = t & 63;
    const int w = t >> 6;

    // =================== PHASE A: prep (block b = batch b; Cs build spread) ==========
    {
        const int b = blockIdx.x;
        {   // Cs = C * rsqrt(psi): 1024 elems per block (k = b>>2, col quarter b&3)
            const int k = b >> 2;
            const int col = ((b & 3) << 10) + t * 2;
            float c0v = C[(size_t)k * NNV + col];
            float c1v = C[(size_t)k * NNV + col + 1];
            float p0 = psi[col], p1 = psi[col + 1];
            u32 wpk = (u32)f2bf(c0v * rsqrtf(p0)) | ((u32)f2bf(c1v * rsqrtf(p1)) << 16);
            *(u32*)(Csbf + (size_t)k * NNV + col) = wpk;
        }
        float* sred = (float*)(smem + OFF_SRED);    // [8][5]
        const float rho_s = rho[0];
        const float lrho = __logf(rho_s);
        const float* tg = targets + (size_t)b * NNV;
        const float* qb = qs + (size_t)b * NNV;
        const float* mb = means + (size_t)b * NNV;

        float s_uni = 0.f, s_wdd = 0.f, s_nb = 0.f, s_mlp = 0.f, s_extra = 0.f;
#pragma unroll
        for (int i = 0; i < 2; ++i) {
            int n4 = i * 2048 + t * 4;
            float4 tv4 = *(const float4*)(tg + n4);
            float4 qv4 = *(const float4*)(qb + n4);
            float4 mu4 = *(const float4*)(mb + n4);
            float4 pv4 = *(const float4*)(psi + n4);
            float tvv[4] = {tv4.x, tv4.y, tv4.z, tv4.w};
            float qv [4] = {qv4.x, qv4.y, qv4.z, qv4.w};
            float muv[4] = {mu4.x, mu4.y, mu4.z, mu4.w};
            float pv [4] = {pv4.x, pv4.y, pv4.z, pv4.w};
            u16 dsv[4]; bool mk[4];
#pragma unroll
            for (int j = 0; j < 4; ++j) {
                bool m = tvv[j] >= rho_s;
                float ds = 0.f;
                if (m) {
                    float y = __logf(tvv[j]);
                    float d = y - muv[j];
                    ds = d * rsqrtf(pv[j]);
                    s_wdd += ds * ds;
                    s_nb += 1.f;
                    s_mlp += __logf(pv[j]);
                    s_extra += __logf(qv[j]) - y;
                } else {
                    s_uni += __logf(1.f - qv[j]) - lrho;
                }
                dsv[j] = f2bf(ds);
                mk[j] = m;
            }
            u32 d0 = (u32)dsv[0] | ((u32)dsv[1] << 16);
            u32 d1 = (u32)dsv[2] | ((u32)dsv[3] << 16);
            u32 m0 = (mk[0] ? 0xFFFFu : 0u) | (mk[1] ? 0xFFFF0000u : 0u);
            u32 m1 = (mk[2] ? 0xFFFFu : 0u) | (mk[3] ? 0xFFFF0000u : 0u);
            *(uint2*)(dsbf + (size_t)b * NNV + n4) = make_uint2(d0, d1);
            *(uint2*)(mask2 + (size_t)b * (NNV/2) + n4/2) = make_uint2(m0, m1);
        }
#pragma unroll
        for (int off = 32; off > 0; off >>= 1) {
            s_uni  += __shfl_down(s_uni, off);
            s_wdd  += __shfl_down(s_wdd, off);
            s_nb   += __shfl_down(s_nb, off);
            s_mlp  += __shfl_down(s_mlp, off);
            s_extra+= __shfl_down(s_extra, off);
        }
        if (lane == 0) {
            sred[w*5+0] = s_uni; sred[w*5+1] = s_wdd; sred[w*5+2] = s_nb;
            sred[w*5+3] = s_mlp; sred[w*5+4] = s_extra;
        }
        __syncthreads();
        if (t == 0) {
            float a0=0,a1=0,a2=0,a3=0,a4=0;
#pragma unroll
            for (int w8 = 0; w8 < 8; ++w8) {
                a0 += sred[w8*5+0]; a1 += sred[w8*5+1]; a2 += sred[w8*5+2];
                a3 += sred[w8*5+3]; a4 += sred[w8*5+4];
            }
            scal[b*5+0]=a0; scal[b*5+1]=a1; scal[b*5+2]=a2; scal[b*5+3]=a3; scal[b*5+4]=a4;
        }
    }
    __threadfence();
    grid.sync();

    // =================== PHASE B: gram (R6 structure, pointer-ized LDS) ==============
    {
        u16* const gbufp  = (u16*)smem;                    // [3][KKV*CHN]
        u16* const dsrowp = (u16*)(smem + OFF_DSROW);      // [2][3][512]
        u32* const m2p    = (u32*)(smem + OFF_M2);         // [2][2048]

        const int bid = blockIdx.x;
        const int nhalf = bid & 1;
        const int pair = bid >> 1;
        const int b0 = pair * 2, b1 = b0 + 1;
        const int c0 = nhalf * (NCH / 2);

        const int half = w & 1;
        const int tilid = w >> 1;
        const int l31 = lane & 31;
        const int hsel = lane >> 5;

        {
            u32x4 v0 = *(const u32x4*)(mask2 + (size_t)b0 * (NNV/2) + t*4);
            *(u32x4*)(&m2p[t*4]) = v0;
            u32x4 v1 = *(const u32x4*)(mask2 + (size_t)b1 * (NNV/2) + t*4);
            *(u32x4*)(&m2p[2048 + t*4]) = v1;
        }

        f32x16 acc0, acc1;
#pragma unroll
        for (int i = 0; i < 16; ++i) { acc0[i] = 0.f; acc1[i] = 0.f; }
        f32x4 ua0, ub0, ua1, ub1;
#pragma unroll
        for (int i = 0; i < 4; ++i) { ua0[i] = 0.f; ub0[i] = 0.f; ua1[i] = 0.f; ub1[i] = 0.f; }

#define STAGE(cc, pp) do {                                                          \
    _Pragma("unroll")                                                               \
    for (int i_ = 0; i_ < 4; ++i_) {                                                \
        int beta0 = w*256 + i_*64;                                                  \
        int beta = beta0 + lane;                                                    \
        int r_ = beta >> 5, blkP = beta & 31;                                       \
        int blkS = blkP ^ (r_ & 15);                                                \
        const u16* src = Csbf + (size_t)r_ * NNV + (cc)*CHN + blkS*8;               \
        __builtin_amdgcn_global_load_lds(                                           \
            (const __attribute__((address_space(1))) void*)src,                     \
            (__attribute__((address_space(3))) void*)(&gbufp[(pp)*(KKV*CHN) + beta0*8]), \
            16, 0, 0);                                                              \
    }                                                                               \
    {                                                                               \
        const u16* s0_ = dsbf + (size_t)b0 * NNV + (cc)*CHN + (lane & 31)*8;        \
        __builtin_amdgcn_global_load_lds(                                           \
            (const __attribute__((address_space(1))) void*)s0_,                     \
            (__attribute__((address_space(3))) void*)(&dsrowp[(pp)*512]),           \
            16, 0, 0);                                                              \
        const u16* s1_ = dsbf + (size_t)b1 * NNV + (cc)*CHN + (lane & 31)*8;        \
        __builtin_amdgcn_global_load_lds(                                           \
            (const __attribute__((address_space(1))) void*)s1_,                     \
            (__attribute__((address_space(3))) void*)(&dsrowp[(3 + (pp))*512]),     \
            16, 0, 0);                                                              \
    }                                                                               \
} while (0)

        STAGE(c0 + 0, 0);
        STAGE(c0 + 1, 1);
        asm volatile("s_waitcnt vmcnt(6) lgkmcnt(0)" ::: "memory");
        __builtin_amdgcn_s_barrier();

#pragma unroll
        for (int cl = 0; cl < NCH / 2; ++cl) {
            const int c = c0 + cl;
            const int p = cl % 3;
            if (cl + 2 < NCH / 2) STAGE(c0 + cl + 2, (cl + 2) % 3);
            const char* gb = (const char*)&gbufp[p * (KKV*CHN)];
            if (w < 6) {
                const int rbA = (tilid == 0) ? 0 : 32;
                const int rbB = (tilid == 2) ? 32 : 0;
                const int rA = rbA + l31, rB = rbB + l31;
                const int swA = (rA & 15) << 4, swB = (rB & 15) << 4;
                const char* mb0 = (const char*)m2p + c*512 + hsel*16;
                const char* mb1 = (const char*)m2p + 8192 + c*512 + hsel*16;
#pragma unroll
                for (int s8 = 0; s8 < 8; ++s8) {
                    const int s = half*8 + s8;
                    const int colbyte = s*32 + hsel*16;
                    u32x4 fB = *(const u32x4*)(gb + rB*512 + (colbyte ^ swB));
                    u32x4 fAr;
                    if (tilid == 1) fAr = *(const u32x4*)(gb + rA*512 + (colbyte ^ swA));
                    else            fAr = fB;
                    u32x4 mk0 = *(const u32x4*)(mb0 + s*32);
                    u32x4 mk1 = *(const u32x4*)(mb1 + s*32);
                    u32x4 fA0 = fAr & mk0;
                    u32x4 fA1 = fAr & mk1;
                    acc0 = __builtin_amdgcn_mfma_f32_32x32x16_bf16(
                            __builtin_bit_cast(bf16x8, fA0),
                            __builtin_bit_cast(bf16x8, fB), acc0, 0, 0, 0);
                    acc1 = __builtin_amdgcn_mfma_f32_32x32x16_bf16(
                            __builtin_bit_cast(bf16x8, fA1),
                            __builtin_bit_cast(bf16x8, fB), acc1, 0, 0, 0);
                }
            } else {
                const int cb0 = (w == 6) ? 0 : 32;
                const int l15 = lane & 15;
                const int g4 = lane >> 4;
                const int r0 = cb0 + l15, r1 = r0 + 16;
                const int sw0 = (r0 & 15) << 4, sw1 = (r1 & 15) << 4;
                const char* dr0 = (const char*)&dsrowp[p * 512];
                const char* dr1 = (const char*)&dsrowp[(3 + p) * 512];
#pragma unroll
                for (int su = 0; su < 8; ++su) {
                    const int colbyte = su*64 + g4*16;
                    u32x4 dv0 = *(const u32x4*)(dr0 + colbyte);
                    u32x4 dv1 = *(const u32x4*)(dr1 + colbyte);
                    if (l15 != 0) { dv0 = dv0 ^ dv0; dv1 = dv1 ^ dv1; }
                    u32x4 f0 = *(const u32x4*)(gb + r0*512 + (colbyte ^ sw0));
                    u32x4 f1 = *(const u32x4*)(gb + r1*512 + (colbyte ^ sw1));
                    ua0 = __builtin_amdgcn_mfma_f32_16x16x32_bf16(
                            __builtin_bit_cast(bf16x8, dv0), __builtin_bit_cast(bf16x8, f0), ua0, 0,0,0);
                    ub0 = __builtin_amdgcn_mfma_f32_16x16x32_bf16(
                            __builtin_bit_cast(bf16x8, dv0), __builtin_bit_cast(bf16x8, f1), ub0, 0,0,0);
                    ua1 = __builtin_amdgcn_mfma_f32_16x16x32_bf16(
                            __builtin_bit_cast(bf16x8, dv1), __builtin_bit_cast(bf16x8, f0), ua1, 0,0,0);
                    ub1 = __builtin_amdgcn_mfma_f32_16x16x32_bf16(
                            __builtin_bit_cast(bf16x8, dv1), __builtin_bit_cast(bf16x8, f1), ub1, 0,0,0);
                }
            }
            if (cl + 2 < NCH / 2) asm volatile("s_waitcnt vmcnt(6) lgkmcnt(0)" ::: "memory");
            else                  asm volatile("s_waitcnt vmcnt(0) lgkmcnt(0)" ::: "memory");
            __builtin_amdgcn_s_barrier();
        }

        float* red0 = (float*)smem;
        float* red1 = (float*)(smem + 32768);
        if (w < 6 && half == 0) {
#pragma unroll
            for (int g = 0; g < 16; ++g) {
                int row = (g & 3) + 8*(g >> 2) + 4*hsel;
                red0[tilid*1024 + row*32 + l31] = acc0[g];
                red1[tilid*1024 + row*32 + l31] = acc1[g];
            }
        }
        if (w >= 6 && lane < 16) {
            const int cb0 = (w == 6) ? 0 : 32;
            float* U0 = Upart + ((size_t)nhalf * BBV + b0) * KKV;
            float* U1 = Upart + ((size_t)nhalf * BBV + b1) * KKV;
            U0[cb0 + lane]      = ua0[0];
            U0[cb0 + 16 + lane] = ub0[0];
            U1[cb0 + lane]      = ua1[0];
            U1[cb0 + 16 + lane] = ub1[0];
        }
        __syncthreads();
        if (w < 6 && half == 1) {
            float* A0 = Apart + ((size_t)nhalf * BBV + b0) * 4096;
            float* A1 = Apart + ((size_t)nhalf * BBV + b1) * 4096;
#pragma unroll
            for (int g = 0; g < 16; ++g) {
                int row = (g & 3) + 8*(g >> 2) + 4*hsel;
                int gr = (tilid == 0) ? row : 32 + row;
                int gc = (tilid == 2) ? 32 + l31 : l31;
                A0[gr*64 + gc] = red0[tilid*1024 + row*32 + l31] + acc0[g];
                A1[gr*64 + gc] = red1[tilid*1024 + row*32 + l31] + acc1[g];
            }
        }
#undef STAGE
    }
    __threadfence();
    grid.sync();

    // =================== PHASE C: series tail (R11, 512-thread indexing) =============
    {
        u16* const Pp = (u16*)smem;                        // [NPW][4096] bf16 swizzled
        float* const wbuf = (float*)(smem + OFF_DSROW);    // 64 f32
        float* const alf  = (float*)(smem + OFF_DSROW + 256);
        float* const tred = (float*)(smem + OFF_DSROW + 512);  // [8][19]

        const int b = blockIdx.x;
        const int wv = w;
        const float* A0 = Apart + (size_t)b * 4096;
        const float* A1 = Apart + ((size_t)BBV + b) * 4096;

        if (wv == 0) {
            float aii = A0[lane * 65] + A1[lane * 65] + 1.0f;
            float tr = aii;
#pragma unroll
            for (int off = 32; off; off >>= 1) tr += __shfl_xor(tr, off);
            float alpha = tr * (1.0f / 64.0f);
            float resid = aii - alpha;
#pragma unroll
            for (int off = 32; off; off >>= 1) resid += __shfl_xor(resid, off);
            if (lane == 0) { alf[0] = alpha; alf[1] = resid / alpha; }
        }
        if (wv == 1) {
            wbuf[lane] = Upart[b * 64 + lane] + Upart[(BBV + b) * 64 + lane];
        }
        __syncthreads();
        const float alpha = alf[0];
        const float rinv = 1.0f / alpha;

        // build X = (A - alpha I)/alpha into P[0]: 512 threads x 1 granule (8 cols)
        {
            const int row = t >> 3;
            const int c0b = (t & 7) * 8;
            u32 pk[4];
#pragma unroll
            for (int e2 = 0; e2 < 4; ++e2) {
                int c = c0b + e2 * 2;
                int i0 = (row < 32 && c     >= 32) ? (c    ) * 64 + row : row * 64 + c;
                int i1 = (row < 32 && c + 1 >= 32) ? (c + 1) * 64 + row : row * 64 + c + 1;
                float v0 = A0[i0] + A1[i0];
                float v1 = A0[i1] + A1[i1];
                if (row == c)     v0 += 1.0f;
                if (row == c + 1) v1 += 1.0f;
                v0 = (v0 - ((row == c    ) ? alpha : 0.f)) * rinv;
                v1 = (v1 - ((row == c + 1) ? alpha : 0.f)) * rinv;
                pk[e2] = (u32)f2bf(v0) | ((u32)f2bf(v1) << 16);
            }
            int gs = (t & 7) ^ (row & 7);
            *(u32x4*)((char*)Pp + row * 128 + gs * 16) = *(u32x4*)pk;
        }
        __syncthreads();

        // P[a] = P[a-1] * X via MFMA, waves 0..3 (others idle, barrier-uniform)
        {
            const int rt = wv >> 1, ct = wv & 1;
            const int l31 = lane & 31, hsel = lane >> 5;
            const int rowA = rt * 32 + l31;
            const int rowB = ct * 32 + l31;
            for (int a = 1; a < NPW; ++a) {
                if (wv < 4) {
                    const char* Pa = (const char*)Pp + (a - 1) * 8192;
                    const char* Px = (const char*)Pp;
                    f32x16 acc;
#pragma unroll
                    for (int i = 0; i < 16; ++i) acc[i] = 0.f;
#pragma unroll
                    for (int s = 0; s < 4; ++s) {
                        int g = s * 2 + hsel;
                        u32x4 fa = *(const u32x4*)(Pa + rowA * 128 + ((g ^ (rowA & 7)) * 16));
                        u32x4 fb = *(const u32x4*)(Px + rowB * 128 + ((g ^ (rowB & 7)) * 16));
                        acc = __builtin_amdgcn_mfma_f32_32x32x16_bf16(
                                __builtin_bit_cast(bf16x8, fa),
                                __builtin_bit_cast(bf16x8, fb), acc, 0, 0, 0);
                    }
#pragma unroll
                    for (int g = 0; g < 16; ++g) {
                        int row = rt * 32 + (g & 3) + 8 * (g >> 2) + 4 * hsel;
                        int col = ct * 32 + l31;
                        int gg = (col >> 3) ^ (row & 7);
                        *(u16*)((char*)Pp + a * 8192 + row * 128 + gg * 16 + (col & 7) * 2) = f2bf(acc[g]);
                    }
                }
                __syncthreads();
            }
        }

        // traces t_2..t_20: 512 threads x 8 elems per power
        {
            float tacc[19];
#pragma unroll
            for (int i = 0; i < 19; ++i) tacc[i] = 0.f;
            const int row = t >> 3;
            const int g0 = (t & 7) ^ (row & 7);
            float prev[8];
#pragma unroll
            for (int a = 0; a < NPW; ++a) {
                u32x4 r0 = *(const u32x4*)((const char*)Pp + a * 8192 + row * 128 + g0 * 16);
                float cur[8];
#pragma unroll
                for (int e = 0; e < 4; ++e) {
                    cur[2*e]     = bf2f((u16)(r0[e] & 0xFFFF));
                    cur[2*e + 1] = bf2f((u16)(r0[e] >> 16));
                }
                float sq = 0.f, cr = 0.f;
#pragma unroll
                for (int e = 0; e < 8; ++e) {
                    sq += cur[e] * cur[e];
                    cr += (a > 0 ? prev[e] : 0.f) * cur[e];
                }
                tacc[2 * a] += sq;
                if (a > 0) tacc[2 * a - 1] += cr;
#pragma unroll
                for (int e = 0; e < 8; ++e) prev[e] = cur[e];
            }
#pragma unroll
            for (int i = 0; i < 19; ++i) {
                float v = tacc[i];
#pragma unroll
                for (int off = 32; off; off >>= 1) v += __shfl_xor(v, off);
                tacc[i] = v;
            }
            if (lane == 0) {
#pragma unroll
                for (int i = 0; i < 19; ++i) tred[wv * 19 + i] = tacc[i];
            }
        }
        __syncthreads();

        // wave 0: Neumann matvec chain + assembly
        if (wv == 0) {
            float wr[NPW + 1];
            wr[0] = wbuf[lane];
            for (int a = 1; a <= NPW; ++a) {
                float acc = 0.f;
#pragma unroll
                for (int g = 0; g < 8; ++g) {
                    u32x4 xr = *(const u32x4*)((const char*)Pp + lane * 128 + ((g ^ (lane & 7)) * 16));
                    f32x4 w0 = *(const f32x4*)(&wbuf[g * 8]);
                    f32x4 w1 = *(const f32x4*)(&wbuf[g * 8 + 4]);
                    acc += bf2f((u16)(xr[0] & 0xFFFF)) * w0[0];
                    acc += bf2f((u16)(xr[0] >> 16))    * w0[1];
                    acc += bf2f((u16)(xr[1] & 0xFFFF)) * w0[2];
                    acc += bf2f((u16)(xr[1] >> 16))    * w0[3];
                    acc += bf2f((u16)(xr[2] & 0xFFFF)) * w1[0];
                    acc += bf2f((u16)(xr[2] >> 16))    * w1[1];
                    acc += bf2f((u16)(xr[3] & 0xFFFF)) * w1[2];
                    acc += bf2f((u16)(xr[3] >> 16))    * w1[3];
                }
                asm volatile("s_waitcnt lgkmcnt(0)" ::: "memory");
                wbuf[lane] = acc;
                asm volatile("s_waitcnt lgkmcnt(0)" ::: "memory");
                wr[a] = acc;
            }
            float sv[21];
#pragma unroll
            for (int p = 0; p <= 20; ++p) sv[p] = wr[p >> 1] * wr[p - (p >> 1)];
#pragma unroll
            for (int p = 0; p <= 20; ++p) {
                float v = sv[p];
#pragma unroll
                for (int off = 32; off; off >>= 1) v += __shfl_xor(v, off);
                sv[p] = v;
            }
            if (lane == 0) {
                float logdet = 64.0f * __logf(alpha) + alf[1];
                float sgn = -1.f;
#pragma unroll
                for (int p = 2; p <= 20; ++p) {
                    float tp = 0.f;
#pragma unroll
                    for (int w8 = 0; w8 < 8; ++w8) tp += tred[w8 * 19 + (p - 2)];
                    logdet += sgn * tp / (float)p;
                    sgn = -sgn;
                }
                float quad = 0.f;
                sgn = 1.f;
#pragma unroll
                for (int p = 0; p <= 20; ++p) { quad += sgn * sv[p]; sgn = -sgn; }
                quad *= rinv;
                float uni = scal[b*5+0], wdd = scal[b*5+1], nb = scal[b*5+2],
                      mlp = scal[b*5+3], extra = scal[b*5+4];
                const float LOG2PI = 1.8378770664093453f;
                out[b] = uni + extra - 0.5f * (nb * LOG2PI + mlp + logdet + (wdd - quad));
            }
        }
    }
}

extern "C" void kernel_launch(void* const* d_in, const int* in_sizes, int n_in,
                              void* d_out, int out_size, void* d_ws, size_t ws_size,
                              hipStream_t stream) {
    const float* targets = (const float*)d_in[0];
    const float* rho     = (const float*)d_in[1];
    const float* qs      = (const float*)d_in[2];
    const float* means   = (const float*)d_in[3];
    const float* C       = (const float*)d_in[4];
    const float* psi     = (const float*)d_in[5];
    float* out = (float*)d_out;

    char* ws = (char*)d_ws;
    u16* Csbf   = (u16*)(ws);                                     // 512 KB
    u16* dsbf   = (u16*)(ws + 0x80000);                           // 2 MB
    u32* mask2  = (u32*)(ws + 0x280000);                          // 2 MB
    float* Apart = (float*)(ws + 0x480000);                       // 8 MB (2 n-halves)
    float* Upart = (float*)(ws + 0xC80000);                       // 128 KB (2 n-halves)
    float* scal  = (float*)(ws + 0xCC0000);                       // 5 KB

    void* args[] = {
        (void*)&targets, (void*)&rho, (void*)&qs, (void*)&means, (void*)&C, (void*)&psi,
        (void*)&Csbf, (void*)&dsbf, (void*)&mask2, (void*)&scal,
        (void*)&Apart, (void*)&Upart, (void*)&out
    };
    hipLaunchCooperativeKernel((void*)fused, dim3(BBV), dim3(512), args, 0, stream);
}

// Round 13
// 41.173 us; speedup vs baseline: 4.9480x; 4.9480x over previous
//
#include <hip/hip_runtime.h>
#include <math.h>

#define NNV 4096   // N
#define KKV 64     // K
#define BBV 256    // B
#define CHN 256    // n-chunk staged in LDS
#define NCH (NNV / CHN)

typedef unsigned short u16;
typedef unsigned int u32;
typedef u32  u32x4  __attribute__((ext_vector_type(4)));
typedef short bf16x8 __attribute__((ext_vector_type(8)));
typedef float f32x4  __attribute__((ext_vector_type(4)));
typedef float f32x16 __attribute__((ext_vector_type(16)));

__device__ inline u16 f2bf(float x) {           // RNE f32 -> bf16
    u32 u = __float_as_uint(x);
    u = u + 0x7FFFu + ((u >> 16) & 1u);
    return (u16)(u >> 16);
}
__device__ inline float bf2f(u16 v) { return __uint_as_float(((u32)v) << 16); }

// ================= K1: elementwise prep (+ Cs build in blocks 256..319) ===========
__global__ __launch_bounds__(256) void prep(
    const float* __restrict__ targets, const float* __restrict__ rho,
    const float* __restrict__ qs, const float* __restrict__ means,
    const float* __restrict__ C, const float* __restrict__ psi,
    u16* __restrict__ Csbf, u16* __restrict__ dsbf,
    u32* __restrict__ mask2, float* __restrict__ scal) {
    const int blk = blockIdx.x;
    const int t = threadIdx.x;

    if (blk >= BBV) {                    // Cs = C * rsqrt(psi), bf16, row-major [64][4096]
        const int k = blk - BBV;
        const float* Crow = C + (size_t)k * NNV;
        u16* Orow = Csbf + (size_t)k * NNV;
#pragma unroll
        for (int i = 0; i < 4; ++i) {
            int n4 = i * 1024 + t * 4;
            float4 cv = *(const float4*)(Crow + n4);
            float4 pv = *(const float4*)(psi + n4);
            u32 w0 = (u32)f2bf(cv.x * rsqrtf(pv.x)) | ((u32)f2bf(cv.y * rsqrtf(pv.y)) << 16);
            u32 w1 = (u32)f2bf(cv.z * rsqrtf(pv.z)) | ((u32)f2bf(cv.w * rsqrtf(pv.w)) << 16);
            *(uint2*)(Orow + n4) = make_uint2(w0, w1);
        }
        return;
    }

    __shared__ float sred[4][5];
    const int b = blk;
    const int lane = t & 63, wid = t >> 6;
    const float rho_s = rho[0];
    const float lrho = __logf(rho_s);
    const float* tg = targets + (size_t)b * NNV;
    const float* qb = qs + (size_t)b * NNV;
    const float* mb = means + (size_t)b * NNV;

    float s_uni = 0.f, s_wdd = 0.f, s_nb = 0.f, s_mlp = 0.f, s_extra = 0.f;
#pragma unroll
    for (int i = 0; i < 4; ++i) {
        int n4 = i * 1024 + t * 4;
        float4 tv4 = *(const float4*)(tg + n4);
        float4 qv4 = *(const float4*)(qb + n4);
        float4 mu4 = *(const float4*)(mb + n4);
        float4 pv4 = *(const float4*)(psi + n4);
        float tvv[4] = {tv4.x, tv4.y, tv4.z, tv4.w};
        float qv [4] = {qv4.x, qv4.y, qv4.z, qv4.w};
        float muv[4] = {mu4.x, mu4.y, mu4.z, mu4.w};
        float pv [4] = {pv4.x, pv4.y, pv4.z, pv4.w};
        u16 dsv[4]; bool mk[4];
#pragma unroll
        for (int j = 0; j < 4; ++j) {
            bool m = tvv[j] >= rho_s;
            float ds = 0.f;
            if (m) {
                float y = __logf(tvv[j]);
                float d = y - muv[j];
                ds = d * rsqrtf(pv[j]);               // ds^2 = w*d^2
                s_wdd += ds * ds;
                s_nb += 1.f;
                s_mlp += __logf(pv[j]);
                s_extra += __logf(qv[j]) - y;
            } else {
                s_uni += __logf(1.f - qv[j]) - lrho;
            }
            dsv[j] = f2bf(ds);
            mk[j] = m;
        }
        u32 d0 = (u32)dsv[0] | ((u32)dsv[1] << 16);
        u32 d1 = (u32)dsv[2] | ((u32)dsv[3] << 16);
        u32 m0 = (mk[0] ? 0xFFFFu : 0u) | (mk[1] ? 0xFFFF0000u : 0u);
        u32 m1 = (mk[2] ? 0xFFFFu : 0u) | (mk[3] ? 0xFFFF0000u : 0u);
        *(uint2*)(dsbf + (size_t)b * NNV + n4) = make_uint2(d0, d1);
        *(uint2*)(mask2 + (size_t)b * (NNV/2) + n4/2) = make_uint2(m0, m1);
    }

#pragma unroll
    for (int off = 32; off > 0; off >>= 1) {
        s_uni  += __shfl_down(s_uni, off);
        s_wdd  += __shfl_down(s_wdd, off);
        s_nb   += __shfl_down(s_nb, off);
        s_mlp  += __shfl_down(s_mlp, off);
        s_extra+= __shfl_down(s_extra, off);
    }
    if (lane == 0) {
        sred[wid][0] = s_uni; sred[wid][1] = s_wdd; sred[wid][2] = s_nb;
        sred[wid][3] = s_mlp; sred[wid][4] = s_extra;
    }
    __syncthreads();
    if (t == 0) {
        float a0=0,a1=0,a2=0,a3=0,a4=0;
#pragma unroll
        for (int w4 = 0; w4 < 4; ++w4) {
            a0 += sred[w4][0]; a1 += sred[w4][1]; a2 += sred[w4][2];
            a3 += sred[w4][3]; a4 += sred[w4][4];
        }
        scal[b*5+0]=a0; scal[b*5+1]=a1; scal[b*5+2]=a2; scal[b*5+3]=a3; scal[b*5+4]=a4;
    }
}

// ========== K2: Gram via MFMA — 2 batches/block share Cs reads, n-split in 2 ==========
// Writes FULL symmetric partial A (A01 mirror added for tail's coalesced reads) + u.
__global__ __launch_bounds__(512, 2) void gram(
    const u16* __restrict__ Csbf, const u16* __restrict__ dsbf,
    const u32* __restrict__ mask2g, float* __restrict__ Apart, float* __restrict__ Upart) {
    __shared__ __align__(16) u16 gbuf[3][KKV * CHN];   // swizzled Cs chunk, 32 KB each
    __shared__ __align__(16) u16 dsrow[2][3][512];     // per-batch ds rows (upper 512B dup)
    __shared__ __align__(16) u32 m2[2][NNV / 2];       // per-batch packed masks, 8 KB each

    const int bid = blockIdx.x;
    const int nhalf = bid & 1;
    const int pair = bid >> 1;
    const int b0 = pair * 2, b1 = b0 + 1;
    const int c0 = nhalf * (NCH / 2);    // first chunk of this block's n-range

    const int t = threadIdx.x;
    const int lane = t & 63;
    const int w = t >> 6;
    const int half = w & 1;
    const int tilid = w >> 1;          // 0,1,2 = A00,A10,A11 ; 3 = u-waves
    const int l31 = lane & 31;
    const int hsel = lane >> 5;

    {   // stage both batches' mask words (full 8 KB each; only our half is read)
        u32x4 v0 = *(const u32x4*)(mask2g + (size_t)b0 * (NNV/2) + t*4);
        *(u32x4*)(&m2[0][t*4]) = v0;
        u32x4 v1 = *(const u32x4*)(mask2g + (size_t)b1 * (NNV/2) + t*4);
        *(u32x4*)(&m2[1][t*4]) = v1;
    }

    f32x16 acc0, acc1;
#pragma unroll
    for (int i = 0; i < 16; ++i) { acc0[i] = 0.f; acc1[i] = 0.f; }
    f32x4 ua0, ub0, ua1, ub1;
#pragma unroll
    for (int i = 0; i < 4; ++i) { ua0[i] = 0.f; ub0[i] = 0.f; ua1[i] = 0.f; ub1[i] = 0.f; }

#define STAGE(cc, pp) do {                                                          \
    _Pragma("unroll")                                                               \
    for (int i_ = 0; i_ < 4; ++i_) {                                                \
        int beta0 = w*256 + i_*64;                                                  \
        int beta = beta0 + lane;                                                    \
        int r_ = beta >> 5, blkP = beta & 31;                                       \
        int blkS = blkP ^ (r_ & 15);   /* source pre-swizzle (m173 pattern) */      \
        const u16* src = Csbf + (size_t)r_ * NNV + (cc)*CHN + blkS*8;               \
        __builtin_amdgcn_global_load_lds(                                           \
            (const __attribute__((address_space(1))) void*)src,                     \
            (__attribute__((address_space(3))) void*)(&gbuf[pp][beta0*8]),          \
            16, 0, 0);                                                              \
    }                                                                               \
    {                                                                               \
        const u16* s0_ = dsbf + (size_t)b0 * NNV + (cc)*CHN + (lane & 31)*8;        \
        __builtin_amdgcn_global_load_lds(                                           \
            (const __attribute__((address_space(1))) void*)s0_,                     \
            (__attribute__((address_space(3))) void*)(&dsrow[0][pp][0]),            \
            16, 0, 0);                                                              \
        const u16* s1_ = dsbf + (size_t)b1 * NNV + (cc)*CHN + (lane & 31)*8;        \
        __builtin_amdgcn_global_load_lds(                                           \
            (const __attribute__((address_space(1))) void*)s1_,                     \
            (__attribute__((address_space(3))) void*)(&dsrow[1][pp][0]),            \
            16, 0, 0);                                                              \
    }                                                                               \
} while (0)

    STAGE(c0 + 0, 0);
    STAGE(c0 + 1, 1);
    asm volatile("s_waitcnt vmcnt(6) lgkmcnt(0)" ::: "memory");
    __builtin_amdgcn_s_barrier();

#pragma unroll
    for (int cl = 0; cl < NCH / 2; ++cl) {
        const int c = c0 + cl;
        const int p = cl % 3;
        if (cl + 2 < NCH / 2) STAGE(c0 + cl + 2, (cl + 2) % 3);
        const char* gb = (const char*)gbuf[p];
        if (w < 6) {
            const int rbA = (tilid == 0) ? 0 : 32;
            const int rbB = (tilid == 2) ? 32 : 0;
            const int rA = rbA + l31, rB = rbB + l31;
            const int swA = (rA & 15) << 4, swB = (rB & 15) << 4;
            const char* mb0 = (const char*)&m2[0][0] + c*512 + hsel*16;
            const char* mb1 = (const char*)&m2[1][0] + c*512 + hsel*16;
#pragma unroll
            for (int s8 = 0; s8 < 8; ++s8) {
                const int s = half*8 + s8;
                const int colbyte = s*32 + hsel*16;
                u32x4 fB = *(const u32x4*)(gb + rB*512 + (colbyte ^ swB));
                u32x4 fAr;
                if (tilid == 1) fAr = *(const u32x4*)(gb + rA*512 + (colbyte ^ swA));
                else            fAr = fB;                      // diag tiles: reuse read
                u32x4 mk0 = *(const u32x4*)(mb0 + s*32);       // broadcast per half-wave
                u32x4 mk1 = *(const u32x4*)(mb1 + s*32);
                u32x4 fA0 = fAr & mk0;                         // mask A-side only (m^2=m)
                u32x4 fA1 = fAr & mk1;
                acc0 = __builtin_amdgcn_mfma_f32_32x32x16_bf16(
                        __builtin_bit_cast(bf16x8, fA0),
                        __builtin_bit_cast(bf16x8, fB), acc0, 0, 0, 0);
                acc1 = __builtin_amdgcn_mfma_f32_32x32x16_bf16(
                        __builtin_bit_cast(bf16x8, fA1),
                        __builtin_bit_cast(bf16x8, fB), acc1, 0, 0, 0);
            }
        } else {
            const int cb0 = (w == 6) ? 0 : 32;
            const int l15 = lane & 15;
            const int g4 = lane >> 4;
            const int r0 = cb0 + l15, r1 = r0 + 16;
            const int sw0 = (r0 & 15) << 4, sw1 = (r1 & 15) << 4;
            const char* dr0 = (const char*)&dsrow[0][p][0];
            const char* dr1 = (const char*)&dsrow[1][p][0];
#pragma unroll
            for (int su = 0; su < 8; ++su) {
                const int colbyte = su*64 + g4*16;
                u32x4 dv0 = *(const u32x4*)(dr0 + colbyte);    // broadcast
                u32x4 dv1 = *(const u32x4*)(dr1 + colbyte);
                if (l15 != 0) { dv0 = dv0 ^ dv0; dv1 = dv1 ^ dv1; }  // A rows 1..15 = 0
                u32x4 f0 = *(const u32x4*)(gb + r0*512 + (colbyte ^ sw0));
                u32x4 f1 = *(const u32x4*)(gb + r1*512 + (colbyte ^ sw1));
                ua0 = __builtin_amdgcn_mfma_f32_16x16x32_bf16(
                        __builtin_bit_cast(bf16x8, dv0), __builtin_bit_cast(bf16x8, f0), ua0, 0,0,0);
                ub0 = __builtin_amdgcn_mfma_f32_16x16x32_bf16(
                        __builtin_bit_cast(bf16x8, dv0), __builtin_bit_cast(bf16x8, f1), ub0, 0,0,0);
                ua1 = __builtin_amdgcn_mfma_f32_16x16x32_bf16(
                        __builtin_bit_cast(bf16x8, dv1), __builtin_bit_cast(bf16x8, f0), ua1, 0,0,0);
                ub1 = __builtin_amdgcn_mfma_f32_16x16x32_bf16(
                        __builtin_bit_cast(bf16x8, dv1), __builtin_bit_cast(bf16x8, f1), ub1, 0,0,0);
            }
        }
        if (cl + 2 < NCH / 2) asm volatile("s_waitcnt vmcnt(6) lgkmcnt(0)" ::: "memory");
        else                  asm volatile("s_waitcnt vmcnt(0) lgkmcnt(0)" ::: "memory");
        __builtin_amdgcn_s_barrier();
    }

    // epilogue: combine s-halves, write partial A tiles (+A01 mirror) + u
    float* red0 = (float*)&gbuf[0][0];
    float* red1 = (float*)&gbuf[1][0];
    if (w < 6 && half == 0) {
#pragma unroll
        for (int g = 0; g < 16; ++g) {
            int row = (g & 3) + 8*(g >> 2) + 4*hsel;          // 32x32 C/D layout (m74/m101)
            red0[tilid*1024 + row*32 + l31] = acc0[g];
            red1[tilid*1024 + row*32 + l31] = acc1[g];
        }
    }
    if (w >= 6 && lane < 16) {                                 // 16x16 D row0 = u
        const int cb0 = (w == 6) ? 0 : 32;
        float* U0 = Upart + ((size_t)nhalf * BBV + b0) * KKV;
        float* U1 = Upart + ((size_t)nhalf * BBV + b1) * KKV;
        U0[cb0 + lane]      = ua0[0];
        U0[cb0 + 16 + lane] = ub0[0];
        U1[cb0 + lane]      = ua1[0];
        U1[cb0 + 16 + lane] = ub1[0];
    }
    __syncthreads();
    if (w < 6 && half == 1) {
        float* A0 = Apart + ((size_t)nhalf * BBV + b0) * 4096;
        float* A1 = Apart + ((size_t)nhalf * BBV + b1) * 4096;
#pragma unroll
        for (int g = 0; g < 16; ++g) {
            int row = (g & 3) + 8*(g >> 2) + 4*hsel;
            int gr = (tilid == 0) ? row : 32 + row;
            int gc = (tilid == 2) ? 32 + l31 : l31;
            float v0 = red0[tilid*1024 + row*32 + l31] + acc0[g];
            float v1 = red1[tilid*1024 + row*32 + l31] + acc1[g];
            A0[gr*64 + gc] = v0;
            A1[gr*64 + gc] = v1;
            if (tilid == 1) {            // A is symmetric: mirror A10 -> A01
                A0[gc*64 + gr] = v0;
                A1[gc*64 + gr] = v1;
            }
        }
    }
#undef STAGE
}

// ======= K3: series tail v2 — binary powering + parallel matvecs =======
// A = alpha(I+X). Powers X^1..X^8 (slots P[0..7]) in 4 MFMA rounds (2 products
// per round on 8 waves). logdet: tr(X^p), p<=16 via streamed Frobenius dots.
// quad: w_a = X^a u, a=1..8 in ONE parallel round; s_p = w_a . w_b, p<=16.
// P bf16 swizzled: byte = row*128 + ((col>>3)^(row&7))*16 + (col&7)*2.
__global__ __launch_bounds__(512, 2) void tail(
    const float* __restrict__ Apart, const float* __restrict__ Upart,
    const float* __restrict__ scal, float* __restrict__ out) {
    __shared__ __align__(16) u16 P[8][4096];     // 64 KB
    __shared__ __align__(16) float wva[9][64];   // w_0..w_8
    __shared__ float alf[2];
    __shared__ float tred[8][15];

    const int b = blockIdx.x;
    const int t = threadIdx.x;
    const int lane = t & 63;
    const int wv = t >> 6;
    const float* A0 = Apart + (size_t)b * 4096;
    const float* A1 = Apart + ((size_t)BBV + b) * 4096;

    // ---- phase 0: alpha + tr(X) (wave 0); u (wave 1) ----
    if (wv == 0) {
        float aii = A0[lane * 65] + A1[lane * 65] + 1.0f;
        float tr = aii;
#pragma unroll
        for (int off = 32; off; off >>= 1) tr += __shfl_xor(tr, off);
        float alpha = tr * (1.0f / 64.0f);
        float resid = aii - alpha;
#pragma unroll
        for (int off = 32; off; off >>= 1) resid += __shfl_xor(resid, off);
        if (lane == 0) { alf[0] = alpha; alf[1] = resid / alpha; }
    }
    if (wv == 1) {
        wva[0][lane] = Upart[b * 64 + lane] + Upart[(BBV + b) * 64 + lane];
    }
    __syncthreads();
    const float alpha = alf[0];
    const float rinv = 1.0f / alpha;

    // ---- build X = (A - alpha I)/alpha into P[0] (A now fully mirrored) ----
    {
        const int row = t >> 3;
        const int c0b = (t & 7) * 8;
        u32 pk[4];
#pragma unroll
        for (int e2 = 0; e2 < 4; ++e2) {
            int c = c0b + e2 * 2;
            float v0 = A0[row * 64 + c]     + A1[row * 64 + c];
            float v1 = A0[row * 64 + c + 1] + A1[row * 64 + c + 1];
            if (row == c)     v0 += 1.0f;
            if (row == c + 1) v1 += 1.0f;
            v0 = (v0 - ((row == c    ) ? alpha : 0.f)) * rinv;
            v1 = (v1 - ((row == c + 1) ? alpha : 0.f)) * rinv;
            pk[e2] = (u32)f2bf(v0) | ((u32)f2bf(v1) << 16);
        }
        int gs = (t & 7) ^ (row & 7);
        *(u32x4*)((char*)&P[0][0] + row * 128 + gs * 16) = *(u32x4*)pk;
    }
    __syncthreads();

    // ---- 4 matmul rounds: binary powering (slot s = X^{s+1}) ----
    // r0: grp0 P1=P0*P0          ; grp1 idle
    // r1: grp0 P2=P0*P1 (X3)     ; grp1 P3=P1*P1 (X4)
    // r2: grp0 P4=P0*P3 (X5)     ; grp1 P5=P1*P3 (X6)
    // r3: grp0 P6=P2*P3 (X7)     ; grp1 P7=P3*P3 (X8)
    {
        const int grp = wv >> 2;
        const int wl = wv & 3;
        const int rt = wl >> 1, ct = wl & 1;
        const int l31 = lane & 31, hsel = lane >> 5;
        const int rowA = rt * 32 + l31;
        const int rowB = ct * 32 + l31;
        const int dstP[4][2] = { {1, -1}, {2, 3}, {4, 5}, {6, 7} };
        const int srcA[4][2] = { {0,  0}, {0, 1}, {0, 1}, {2, 3} };
        const int srcB[4][2] = { {0,  0}, {1, 1}, {3, 3}, {3, 3} };
#pragma unroll
        for (int r = 0; r < 4; ++r) {
            int dst = dstP[r][grp];
            if (dst >= 0) {
                const char* Pa = (const char*)&P[srcA[r][grp]][0];
                const char* Pb = (const char*)&P[srcB[r][grp]][0];
                f32x16 acc;
#pragma unroll
                for (int i = 0; i < 16; ++i) acc[i] = 0.f;
#pragma unroll
                for (int s = 0; s < 4; ++s) {
                    int g = s * 2 + hsel;
                    u32x4 fa = *(const u32x4*)(Pa + rowA * 128 + ((g ^ (rowA & 7)) * 16));
                    u32x4 fb = *(const u32x4*)(Pb + rowB * 128 + ((g ^ (rowB & 7)) * 16));
                    acc = __builtin_amdgcn_mfma_f32_32x32x16_bf16(
                            __builtin_bit_cast(bf16x8, fa),
                            __builtin_bit_cast(bf16x8, fb), acc, 0, 0, 0);
                }
#pragma unroll
                for (int g = 0; g < 16; ++g) {
                    int row = rt * 32 + (g & 3) + 8 * (g >> 2) + 4 * hsel;
                    int col = ct * 32 + l31;
                    int gg = (col >> 3) ^ (row & 7);
                    *(u16*)((char*)&P[dst][0] + row * 128 + gg * 16 + (col & 7) * 2) = f2bf(acc[g]);
                }
            }
            __syncthreads();
        }
    }

    // ---- traces tr(X^p), p=2..16 (streamed Frobenius; swizzle cancels) ----
    {
        float tacc[15];
#pragma unroll
        for (int i = 0; i < 15; ++i) tacc[i] = 0.f;
        const int row = t >> 3;
        const int g0 = (t & 7) ^ (row & 7);
        float prev[8];
#pragma unroll
        for (int a = 0; a < 8; ++a) {
            u32x4 r0 = *(const u32x4*)((const char*)&P[a][0] + row * 128 + g0 * 16);
            float cur[8];
#pragma unroll
            for (int e = 0; e < 4; ++e) {
                cur[2*e]     = bf2f((u16)(r0[e] & 0xFFFF));
                cur[2*e + 1] = bf2f((u16)(r0[e] >> 16));
            }
            float sq = 0.f, cr = 0.f;
#pragma unroll
            for (int e = 0; e < 8; ++e) {
                sq += cur[e] * cur[e];
                cr += (a > 0 ? prev[e] : 0.f) * cur[e];
            }
            if (2 * a <= 14) tacc[2 * a] += sq;        // p = 2a+2
            if (a > 0) tacc[2 * a - 1] += cr;          // p = 2a+1
#pragma unroll
            for (int e = 0; e < 8; ++e) prev[e] = cur[e];
        }
#pragma unroll
        for (int i = 0; i < 15; ++i) {
            float v = tacc[i];
#pragma unroll
            for (int off = 32; off; off >>= 1) v += __shfl_xor(v, off);
            tacc[i] = v;
        }
        if (lane == 0) {
#pragma unroll
            for (int i = 0; i < 15; ++i) tred[wv][i] = tacc[i];
        }
    }
    __syncthreads();

    // ---- parallel matvec round: wave a computes w_{a+1} = X^{a+1} u ----
    {
        const char* Pa = (const char*)&P[wv][0];
        float acc = 0.f;
#pragma unroll
        for (int g = 0; g < 8; ++g) {
            u32x4 xr = *(const u32x4*)(Pa + lane * 128 + ((g ^ (lane & 7)) * 16));
            acc += bf2f((u16)(xr[0] & 0xFFFF)) * wva[0][g*8+0];
            acc += bf2f((u16)(xr[0] >> 16))    * wva[0][g*8+1];
            acc += bf2f((u16)(xr[1] & 0xFFFF)) * wva[0][g*8+2];
            acc += bf2f((u16)(xr[1] >> 16))    * wva[0][g*8+3];
            acc += bf2f((u16)(xr[2] & 0xFFFF)) * wva[0][g*8+4];
            acc += bf2f((u16)(xr[2] >> 16))    * wva[0][g*8+5];
            acc += bf2f((u16)(xr[3] & 0xFFFF)) * wva[0][g*8+6];
            acc += bf2f((u16)(xr[3] >> 16))    * wva[0][g*8+7];
        }
        wva[wv + 1][lane] = acc;
    }
    __syncthreads();

    // ---- final: s_p dots + series assembly (wave 0) ----
    if (wv == 0) {
        float sv[17];
#pragma unroll
        for (int p = 0; p <= 16; ++p) sv[p] = wva[p >> 1][lane] * wva[p - (p >> 1)][lane];
#pragma unroll
        for (int p = 0; p <= 16; ++p) {
            float v = sv[p];
#pragma unroll
            for (int off = 32; off; off >>= 1) v += __shfl_xor(v, off);
            sv[p] = v;
        }
        if (lane == 0) {
            float logdet = 64.0f * __logf(alpha) + alf[1];     // p=1 term = tr(X)
            float sgn = -1.f;
#pragma unroll
            for (int p = 2; p <= 16; ++p) {
                float tp = 0.f;
#pragma unroll
                for (int w8 = 0; w8 < 8; ++w8) tp += tred[w8][p - 2];
                logdet += sgn * tp / (float)p;
                sgn = -sgn;
            }
            float quad = 0.f;
            sgn = 1.f;
#pragma unroll
            for (int p = 0; p <= 16; ++p) { quad += sgn * sv[p]; sgn = -sgn; }
            quad *= rinv;
            float uni = scal[b*5+0], wdd = scal[b*5+1], nb = scal[b*5+2],
                  mlp = scal[b*5+3], extra = scal[b*5+4];
            const float LOG2PI = 1.8378770664093453f;
            out[b] = uni + extra - 0.5f * (nb * LOG2PI + mlp + logdet + (wdd - quad));
        }
    }
}

extern "C" void kernel_launch(void* const* d_in, const int* in_sizes, int n_in,
                              void* d_out, int out_size, void* d_ws, size_t ws_size,
                              hipStream_t stream) {
    const float* targets = (const float*)d_in[0];
    const float* rho     = (const float*)d_in[1];
    const float* qs      = (const float*)d_in[2];
    const float* means   = (const float*)d_in[3];
    const float* C       = (const float*)d_in[4];
    const float* psi     = (const float*)d_in[5];
    float* out = (float*)d_out;

    char* ws = (char*)d_ws;
    u16* Csbf   = (u16*)(ws);                                     // 512 KB
    u16* dsbf   = (u16*)(ws + 0x80000);                           // 2 MB
    u32* mask2  = (u32*)(ws + 0x280000);                          // 2 MB
    float* Apart = (float*)(ws + 0x480000);                       // 8 MB (2 n-halves)
    float* Upart = (float*)(ws + 0xC80000);                       // 128 KB (2 n-halves)
    float* scal  = (float*)(ws + 0xCC0000);                       // 5 KB

    prep<<<BBV + KKV, 256, 0, stream>>>(targets, rho, qs, means, C, psi,
                                        Csbf, dsbf, mask2, scal);
    gram<<<BBV, 512, 0, stream>>>(Csbf, dsbf, mask2, Apart, Upart);
    tail<<<BBV, 256 /*unused*/ == 0 ? 256 : 512, 0, stream>>>(Apart, Upart, scal, out);
}